// Round 4
// baseline (258.701 us; speedup 1.0000x reference)
//
#include <hip/hip_runtime.h>
#include <math.h>

#define IMG_H    512
#define IMG_W    512
#define IMG_HW   (IMG_H * IMG_W)
#define N_IMG    128
#define STRIPS   8
#define NBINS    256

typedef float f32x4 __attribute__((ext_vector_type(4)));

// ---------------------------------------------------------------------------
// Fused GLCM kernel: 1024 blocks = 8 strips x 128 images, 256 threads.
// Phase 1: per-strip 256-bin joint histogram (4 angles, wraparound roll)
//          into 4 per-wave LDS histograms, then global atomicAdd per bin.
// Phase 2: last-arriving block of each image computes entropy, publishes the
//          float bits through a device-scope release flag (entropy > 0 always,
//          so bits != 0 serves as the "ready" signal).
// Phase 3: all 8 blocks of the image acquire-spin on the flag, then fill
//          their 1/8 of the output slice with nontemporal float4 stores.
// Cross-image independence pipelines HBM reads (phase 1) against HBM writes
// (phase 3). All 1024 blocks are co-resident (cap 2048 at 4 waves + 4KB LDS),
// so the spin cannot deadlock.
// ---------------------------------------------------------------------------
__global__ __launch_bounds__(256) void glcm_fused_kernel(
    const float* __restrict__ x, float* __restrict__ out,
    unsigned int* __restrict__ hist, unsigned int* __restrict__ done,
    unsigned int* __restrict__ flag) {

    __shared__ unsigned int lh[4][NBINS];
    __shared__ float partial[4];
    __shared__ unsigned int ticket_s;
    __shared__ float ent_s;

    const int tid   = threadIdx.x;
    const int wave  = tid >> 6;
    const int bid   = blockIdx.x;
    const int img   = bid >> 3;
    const int strip = bid & 7;

    for (int i = tid; i < 4 * NBINS; i += 256) ((unsigned int*)lh)[i] = 0u;
    __syncthreads();

    const float* __restrict__ base = x + (size_t)img * IMG_HW;
    unsigned int* mh = lh[wave];

    // 256 threads cover 2 rows per iteration, 4 pixels per thread.
    const int half = tid >> 7;            // which of the two rows
    const int jj   = (tid & 127) << 2;    // first column [0..508]
    const int jm1  = (jj + IMG_W - 1) & (IMG_W - 1);
    const int jp4  = (jj + 4) & (IMG_W - 1);
    const int rowBase = strip * (IMG_H / STRIPS);

    for (int it = 0; it < (IMG_H / STRIPS) / 2; ++it) {
        const int r  = rowBase + it * 2 + half;
        const int ru = (r + IMG_H - 1) & (IMG_H - 1);  // row above (wrap)

        const float4 c4 = *reinterpret_cast<const float4*>(base + (size_t)r  * IMG_W + jj);
        const float4 u4 = *reinterpret_cast<const float4*>(base + (size_t)ru * IMG_W + jj);
        const float  cm1 = base[(size_t)r  * IMG_W + jm1];   // L1 hits (neighbor lines)
        const float  um1 = base[(size_t)ru * IMG_W + jm1];
        const float  up4 = base[(size_t)ru * IMG_W + jp4];

        int qc[5];   // qc[0]=left-of-first, qc[1..4]=the 4 pixels
        int qu[6];   // qu[0]=up-left, qu[1..4]=up row, qu[5]=up-right-of-last
        qc[0] = (int)(cm1 * 15.0f);
        qc[1] = (int)(c4.x * 15.0f); qc[2] = (int)(c4.y * 15.0f);
        qc[3] = (int)(c4.z * 15.0f); qc[4] = (int)(c4.w * 15.0f);
        qu[0] = (int)(um1 * 15.0f);
        qu[1] = (int)(u4.x * 15.0f); qu[2] = (int)(u4.y * 15.0f);
        qu[3] = (int)(u4.z * 15.0f); qu[4] = (int)(u4.w * 15.0f);
        qu[5] = (int)(up4 * 15.0f);

        #pragma unroll
        for (int k = 0; k < 4; ++k) {
            const int q = qc[k + 1] << 4;
            atomicAdd(&mh[q + qc[k]],     1u);  // angle   0 (left)
            atomicAdd(&mh[q + qu[k + 2]], 1u);  // angle  45 (up-right)
            atomicAdd(&mh[q + qu[k + 1]], 1u);  // angle  90 (up)
            atomicAdd(&mh[q + qu[k]],     1u);  // angle 135 (up-left)
        }
    }

    __syncthreads();
    // tid == bin index; merge wave copies, one device-scope atomic per bin.
    const unsigned int total = lh[0][tid] + lh[1][tid] + lh[2][tid] + lh[3][tid];
    atomicAdd(&hist[img * NBINS + tid], total);
    __threadfence();                       // release our adds before ticket
    __syncthreads();
    if (tid == 0) ticket_s = atomicAdd(&done[img], 1u);
    __syncthreads();

    if (ticket_s == 7u) {                  // last block: entropy + publish
        __threadfence();                   // acquire other blocks' adds
        const unsigned int c = __hip_atomic_load(&hist[img * NBINS + tid],
                                                 __ATOMIC_RELAXED,
                                                 __HIP_MEMORY_SCOPE_AGENT);
        const float p = (float)c * (1.0f / 1048576.0f);  // sum == 2^20 exact
        float t = p * logf(p + 1e-10f);
        #pragma unroll
        for (int off = 32; off > 0; off >>= 1) t += __shfl_down(t, off, 64);
        if ((tid & 63) == 0) partial[wave] = t;
        __syncthreads();
        if (tid == 0) {
            const float e = -(partial[0] + partial[1] + partial[2] + partial[3]);
            __hip_atomic_store(&flag[img], __float_as_uint(e),
                               __ATOMIC_RELEASE, __HIP_MEMORY_SCOPE_AGENT);
        }
    }

    // wait for this image's entropy (flag payload = float bits, always != 0)
    if (tid == 0) {
        unsigned int fb;
        while ((fb = __hip_atomic_load(&flag[img], __ATOMIC_ACQUIRE,
                                       __HIP_MEMORY_SCOPE_AGENT)) == 0u)
            __builtin_amdgcn_s_sleep(2);
        ent_s = __uint_as_float(fb);
    }
    __syncthreads();

    // fill: this block's 1/8 slice = 8192 float4, streaming stores
    const float e = ent_s;
    const f32x4 v = {e, e, e, e};
    f32x4* ob = reinterpret_cast<f32x4*>(out) +
                (size_t)img * (IMG_HW / 4) + strip * (IMG_HW / 4 / STRIPS);
    #pragma unroll 4
    for (int i = tid; i < IMG_HW / 4 / STRIPS; i += 256)
        __builtin_nontemporal_store(v, ob + i);
}

extern "C" void kernel_launch(void* const* d_in, const int* in_sizes, int n_in,
                              void* d_out, int out_size, void* d_ws, size_t ws_size,
                              hipStream_t stream) {
    const float* x = (const float*)d_in[0];
    float* out = (float*)d_out;

    unsigned int* hist = (unsigned int*)d_ws;                       // 128*256 u32
    unsigned int* done = hist + N_IMG * NBINS;                      // 128 u32
    unsigned int* flag = done + N_IMG;                              // 128 u32

    // hist/done/flag must start at zero every call (graph replays reuse d_ws)
    (void)hipMemsetAsync(d_ws, 0,
                         (size_t)(N_IMG * NBINS + 2 * N_IMG) * sizeof(unsigned int),
                         stream);

    glcm_fused_kernel<<<N_IMG * STRIPS, 256, 0, stream>>>(x, out, hist, done, flag);
}

// Round 5
// 69.714 us; speedup vs baseline: 3.7109x; 3.7109x over previous
//
#include <hip/hip_runtime.h>
#include <math.h>

#define IMG_H    512
#define IMG_W    512
#define IMG_HW   (IMG_H * IMG_W)
#define N_IMG    128
#define STRIPS   8
#define NBINS    256
#define FILL_PER_IMG 16   // fill blocks per image

typedef float f32x4 __attribute__((ext_vector_type(4)));

// ---------------------------------------------------------------------------
// Kernel 1: per-(image,strip) 256-bin joint histogram over 4 angles
// (wraparound roll semantics). 1024 blocks = 128 images x 8 strips.
// 8 per-half-wave LDS histograms (tid>>5) to halve bank-conflict multiplicity.
// Output: plain stores of the strip-partial histogram (no atomics, no memset).
// ---------------------------------------------------------------------------
__global__ __launch_bounds__(256) void glcm_hist_kernel(
    const float* __restrict__ x, unsigned int* __restrict__ partial) {

    __shared__ unsigned int lh[8][NBINS];
    const int tid   = threadIdx.x;
    const int bid   = blockIdx.x;
    const int img   = bid >> 3;
    const int strip = bid & 7;

    #pragma unroll
    for (int i = tid; i < 8 * NBINS; i += 256) ((unsigned int*)lh)[i] = 0u;
    __syncthreads();

    const float* __restrict__ base = x + (size_t)img * IMG_HW;
    unsigned int* mh = lh[tid >> 5];      // per-half-wave private histogram

    // 256 threads cover 2 rows per iteration, 4 pixels per thread.
    const int half = tid >> 7;            // which of the two rows
    const int jj   = (tid & 127) << 2;    // first column [0..508]
    const int jm1  = (jj + IMG_W - 1) & (IMG_W - 1);
    const int jp4  = (jj + 4) & (IMG_W - 1);
    const int rowBase = strip * (IMG_H / STRIPS);

    for (int it = 0; it < (IMG_H / STRIPS) / 2; ++it) {
        const int r  = rowBase + it * 2 + half;
        const int ru = (r + IMG_H - 1) & (IMG_H - 1);  // row above (wrap)

        const float4 c4 = *reinterpret_cast<const float4*>(base + (size_t)r  * IMG_W + jj);
        const float4 u4 = *reinterpret_cast<const float4*>(base + (size_t)ru * IMG_W + jj);
        const float  cm1 = base[(size_t)r  * IMG_W + jm1];   // L1/L2 hits
        const float  um1 = base[(size_t)ru * IMG_W + jm1];
        const float  up4 = base[(size_t)ru * IMG_W + jp4];

        int qc[5];   // qc[0]=left-of-first, qc[1..4]=the 4 pixels
        int qu[6];   // qu[0]=up-left, qu[1..4]=up row, qu[5]=up-right-of-last
        qc[0] = (int)(cm1 * 15.0f);
        qc[1] = (int)(c4.x * 15.0f); qc[2] = (int)(c4.y * 15.0f);
        qc[3] = (int)(c4.z * 15.0f); qc[4] = (int)(c4.w * 15.0f);
        qu[0] = (int)(um1 * 15.0f);
        qu[1] = (int)(u4.x * 15.0f); qu[2] = (int)(u4.y * 15.0f);
        qu[3] = (int)(u4.z * 15.0f); qu[4] = (int)(u4.w * 15.0f);
        qu[5] = (int)(up4 * 15.0f);

        #pragma unroll
        for (int k = 0; k < 4; ++k) {
            const int q = qc[k + 1] << 4;
            atomicAdd(&mh[q + qc[k]],     1u);  // angle   0 (left)
            atomicAdd(&mh[q + qu[k + 2]], 1u);  // angle  45 (up-right)
            atomicAdd(&mh[q + qu[k + 1]], 1u);  // angle  90 (up)
            atomicAdd(&mh[q + qu[k]],     1u);  // angle 135 (up-left)
        }
    }

    __syncthreads();
    // tid == bin index; merge 8 half-wave copies (stride-256 word reads =
    // 2-way bank aliasing, free), one plain store per bin.
    unsigned int total = 0;
    #pragma unroll
    for (int h = 0; h < 8; ++h) total += lh[h][tid];
    partial[(size_t)(img * STRIPS + strip) * NBINS + tid] = total;
}

// ---------------------------------------------------------------------------
// Kernel 2: fused entropy + broadcast-fill. 2048 blocks = 128 images x 16.
// Each block redundantly computes its image's entropy from the 8 strip
// partials (8KB, L2-hot), then fills its 1/16 of the output slice with
// nontemporal float4 stores. counts.sum() == 4*H*W == 2^20 exactly.
// ---------------------------------------------------------------------------
__global__ __launch_bounds__(256) void glcm_entfill_kernel(
    const unsigned int* __restrict__ partial, float* __restrict__ out) {

    __shared__ float psum[4];
    __shared__ float ent_s;
    const int tid = threadIdx.x;
    const int bid = blockIdx.x;
    const int img = bid >> 4;
    const int sub = bid & 15;

    unsigned int c = 0;
    #pragma unroll
    for (int s = 0; s < STRIPS; ++s)
        c += partial[(size_t)(img * STRIPS + s) * NBINS + tid];

    const float p = (float)c * (1.0f / 1048576.0f);   // exact pow2 scale
    float t = p * logf(p + 1e-10f);
    #pragma unroll
    for (int off = 32; off > 0; off >>= 1) t += __shfl_down(t, off, 64);
    if ((tid & 63) == 0) psum[tid >> 6] = t;
    __syncthreads();
    if (tid == 0) ent_s = -(psum[0] + psum[1] + psum[2] + psum[3]);
    __syncthreads();

    const float e = ent_s;
    const f32x4 v = {e, e, e, e};
    f32x4* ob = reinterpret_cast<f32x4*>(out) +
                (size_t)img * (IMG_HW / 4) + (size_t)sub * (IMG_HW / 4 / FILL_PER_IMG);
    #pragma unroll
    for (int i = tid; i < IMG_HW / 4 / FILL_PER_IMG; i += 256)   // 16 stores/thread
        __builtin_nontemporal_store(v, ob + i);
}

extern "C" void kernel_launch(void* const* d_in, const int* in_sizes, int n_in,
                              void* d_out, int out_size, void* d_ws, size_t ws_size,
                              hipStream_t stream) {
    const float* x = (const float*)d_in[0];
    float* out = (float*)d_out;
    unsigned int* partial = (unsigned int*)d_ws;   // 128*8*256 u32 = 1 MB

    glcm_hist_kernel<<<N_IMG * STRIPS, 256, 0, stream>>>(x, partial);
    glcm_entfill_kernel<<<N_IMG * FILL_PER_IMG, 256, 0, stream>>>(partial, out);
}

// Round 6
// 67.963 us; speedup vs baseline: 3.8065x; 1.0258x over previous
//
#include <hip/hip_runtime.h>
#include <math.h>

#define IMG_H    512
#define IMG_W    512
#define IMG_HW   (IMG_H * IMG_W)
#define N_IMG    128
#define NBINS    256
#define FILL_PER_IMG 16   // fill blocks per image

typedef float f32x4 __attribute__((ext_vector_type(4)));

// ---------------------------------------------------------------------------
// Kernel 1: per-(image,strip) 256-bin joint histogram over 4 angles
// (wraparound roll semantics). Grid = N_IMG * NSTRIPS blocks, 256 threads.
// 8 per-half-wave LDS histograms; plain stores of strip partials (no atomics,
// no memset). Software-pipelined: next row-pair loads issued before the
// current atomic burst so L3 latency hides under DS traffic.
// ---------------------------------------------------------------------------
template<int NSTRIPS>
__global__ __launch_bounds__(256) void glcm_hist_kernel(
    const float* __restrict__ x, unsigned int* __restrict__ partial) {

    constexpr int ROWS  = IMG_H / NSTRIPS;
    constexpr int ITERS = ROWS / 2;

    __shared__ unsigned int lh[8][NBINS];
    const int tid   = threadIdx.x;
    const int bid   = blockIdx.x;
    const int img   = bid / NSTRIPS;
    const int strip = bid % NSTRIPS;

    #pragma unroll
    for (int i = tid; i < 8 * NBINS; i += 256) ((unsigned int*)lh)[i] = 0u;
    __syncthreads();

    const float* __restrict__ base = x + (size_t)img * IMG_HW;
    unsigned int* mh = lh[tid >> 5];      // per-half-wave private histogram

    // 256 threads cover 2 rows per iteration, 4 pixels per thread.
    const int half = tid >> 7;            // which of the two rows
    const int jj   = (tid & 127) << 2;    // first column [0..508]
    const int jm1  = (jj + IMG_W - 1) & (IMG_W - 1);
    const int jp4  = (jj + 4) & (IMG_W - 1);
    const int rowBase = strip * ROWS;

    float4 c4, u4; float cm1, um1, up4;
    {   // prologue load (it = 0)
        const int r  = rowBase + half;
        const int ru = (r + IMG_H - 1) & (IMG_H - 1);
        c4  = *reinterpret_cast<const float4*>(base + (size_t)r  * IMG_W + jj);
        u4  = *reinterpret_cast<const float4*>(base + (size_t)ru * IMG_W + jj);
        cm1 = base[(size_t)r  * IMG_W + jm1];
        um1 = base[(size_t)ru * IMG_W + jm1];
        up4 = base[(size_t)ru * IMG_W + jp4];
    }

    for (int it = 0; it < ITERS; ++it) {
        float4 nc4, nu4; float ncm1, num1, nup4;
        if (it + 1 < ITERS) {             // prefetch next row pair
            const int r  = rowBase + (it + 1) * 2 + half;
            const int ru = (r + IMG_H - 1) & (IMG_H - 1);
            nc4  = *reinterpret_cast<const float4*>(base + (size_t)r  * IMG_W + jj);
            nu4  = *reinterpret_cast<const float4*>(base + (size_t)ru * IMG_W + jj);
            ncm1 = base[(size_t)r  * IMG_W + jm1];
            num1 = base[(size_t)ru * IMG_W + jm1];
            nup4 = base[(size_t)ru * IMG_W + jp4];
        }

        int qc[5];   // qc[0]=left-of-first, qc[1..4]=the 4 pixels
        int qu[6];   // qu[0]=up-left, qu[1..4]=up row, qu[5]=up-right-of-last
        qc[0] = (int)(cm1 * 15.0f);
        qc[1] = (int)(c4.x * 15.0f); qc[2] = (int)(c4.y * 15.0f);
        qc[3] = (int)(c4.z * 15.0f); qc[4] = (int)(c4.w * 15.0f);
        qu[0] = (int)(um1 * 15.0f);
        qu[1] = (int)(u4.x * 15.0f); qu[2] = (int)(u4.y * 15.0f);
        qu[3] = (int)(u4.z * 15.0f); qu[4] = (int)(u4.w * 15.0f);
        qu[5] = (int)(up4 * 15.0f);

        #pragma unroll
        for (int k = 0; k < 4; ++k) {
            const int q = qc[k + 1] << 4;
            atomicAdd(&mh[q + qc[k]],     1u);  // angle   0 (left)
            atomicAdd(&mh[q + qu[k + 2]], 1u);  // angle  45 (up-right)
            atomicAdd(&mh[q + qu[k + 1]], 1u);  // angle  90 (up)
            atomicAdd(&mh[q + qu[k]],     1u);  // angle 135 (up-left)
        }

        c4 = nc4; u4 = nu4; cm1 = ncm1; um1 = num1; up4 = nup4;
    }

    __syncthreads();
    // tid == bin index; merge 8 half-wave copies (stride-256 word reads =
    // 2-way bank aliasing, free), one plain store per bin.
    unsigned int total = 0;
    #pragma unroll
    for (int h = 0; h < 8; ++h) total += lh[h][tid];
    partial[(size_t)(img * NSTRIPS + strip) * NBINS + tid] = total;
}

// ---------------------------------------------------------------------------
// Kernel 2: fused entropy + broadcast-fill. 2048 blocks = 128 images x 16.
// Each block redundantly computes its image's entropy from the strip
// partials (L2-hot), then fills its 1/16 slice with nontemporal stores.
// counts.sum() == 4*H*W == 2^20 exactly.
// ---------------------------------------------------------------------------
template<int NSTRIPS>
__global__ __launch_bounds__(256) void glcm_entfill_kernel(
    const unsigned int* __restrict__ partial, float* __restrict__ out) {

    __shared__ float psum[4];
    __shared__ float ent_s;
    const int tid = threadIdx.x;
    const int bid = blockIdx.x;
    const int img = bid >> 4;
    const int sub = bid & 15;

    unsigned int c = 0;
    #pragma unroll
    for (int s = 0; s < NSTRIPS; ++s)
        c += partial[(size_t)(img * NSTRIPS + s) * NBINS + tid];

    const float p = (float)c * (1.0f / 1048576.0f);   // exact pow2 scale
    float t = p * logf(p + 1e-10f);
    #pragma unroll
    for (int off = 32; off > 0; off >>= 1) t += __shfl_down(t, off, 64);
    if ((tid & 63) == 0) psum[tid >> 6] = t;
    __syncthreads();
    if (tid == 0) ent_s = -(psum[0] + psum[1] + psum[2] + psum[3]);
    __syncthreads();

    const float e = ent_s;
    const f32x4 v = {e, e, e, e};
    f32x4* ob = reinterpret_cast<f32x4*>(out) +
                (size_t)img * (IMG_HW / 4) + (size_t)sub * (IMG_HW / 4 / FILL_PER_IMG);
    #pragma unroll
    for (int i = tid; i < IMG_HW / 4 / FILL_PER_IMG; i += 256)   // 16 stores/thread
        __builtin_nontemporal_store(v, ob + i);
}

extern "C" void kernel_launch(void* const* d_in, const int* in_sizes, int n_in,
                              void* d_out, int out_size, void* d_ws, size_t ws_size,
                              hipStream_t stream) {
    const float* x = (const float*)d_in[0];
    float* out = (float*)d_out;
    unsigned int* partial = (unsigned int*)d_ws;

    if (ws_size >= (size_t)N_IMG * 16 * NBINS * sizeof(unsigned int)) {
        // 16 strips: 2048 blocks (8/CU) for latency hiding in the hist phase
        glcm_hist_kernel<16><<<N_IMG * 16, 256, 0, stream>>>(x, partial);
        glcm_entfill_kernel<16><<<N_IMG * FILL_PER_IMG, 256, 0, stream>>>(partial, out);
    } else {
        glcm_hist_kernel<8><<<N_IMG * 8, 256, 0, stream>>>(x, partial);
        glcm_entfill_kernel<8><<<N_IMG * FILL_PER_IMG, 256, 0, stream>>>(partial, out);
    }
}

// Round 7
// 64.135 us; speedup vs baseline: 4.0337x; 1.0597x over previous
//
#include <hip/hip_runtime.h>
#include <math.h>

#define IMG_H    512
#define IMG_W    512
#define IMG_HW   (IMG_H * IMG_W)
#define N_IMG    128
#define NSTRIPS  8
#define NBINS    256
#define FILL_PER_IMG 16   // fill blocks per image

typedef float f32x4 __attribute__((ext_vector_type(4)));

// ---------------------------------------------------------------------------
// Kernel 1: per-(image,strip) 256-bin joint histogram over 4 angles
// (wraparound roll semantics). 1024 blocks = 128 images x 8 strips.
//
// Bank-conflict-free LDS histogram: counters are per-LANE columns of packed
// 2x16-bit fields. word index = (bin>>1)*64 + lane  ->  bank == lane%32, so
// every ds_add_u32 is exactly 2 lanes/bank (free) and perfectly balanced,
// regardless of the data. Cross-wave same-address safety via atomicAdd.
// Max increments per 16-bit field = 4 waves * 256 <= 1024, no overflow.
// ---------------------------------------------------------------------------
__global__ __launch_bounds__(256) void glcm_hist_kernel(
    const float* __restrict__ x, unsigned int* __restrict__ partial) {

    constexpr int ROWS  = IMG_H / NSTRIPS;   // 64
    constexpr int ITERS = ROWS / 2;          // 32

    __shared__ unsigned int lh[128 * 64];    // 32 KB: 128 bin-pairs x 64 lanes
    const int tid   = threadIdx.x;
    const int lane  = tid & 63;
    const int bid   = blockIdx.x;
    const int img   = bid >> 3;
    const int strip = bid & 7;

    #pragma unroll
    for (int i = tid; i < 128 * 64; i += 256) lh[i] = 0u;
    __syncthreads();

    const float* __restrict__ base = x + (size_t)img * IMG_HW;

    // 256 threads cover 2 rows per iteration, 4 pixels per thread.
    const int half = tid >> 7;            // which of the two rows
    const int jj   = (tid & 127) << 2;    // first column [0..508]
    const int jm1  = (jj + IMG_W - 1) & (IMG_W - 1);
    const int jp4  = (jj + 4) & (IMG_W - 1);
    const int rowBase = strip * ROWS;

    float4 c4, u4; float cm1, um1, up4;
    {   // prologue load (it = 0)
        const int r  = rowBase + half;
        const int ru = (r + IMG_H - 1) & (IMG_H - 1);
        c4  = *reinterpret_cast<const float4*>(base + (size_t)r  * IMG_W + jj);
        u4  = *reinterpret_cast<const float4*>(base + (size_t)ru * IMG_W + jj);
        cm1 = base[(size_t)r  * IMG_W + jm1];
        um1 = base[(size_t)ru * IMG_W + jm1];
        up4 = base[(size_t)ru * IMG_W + jp4];
    }

    for (int it = 0; it < ITERS; ++it) {
        float4 nc4, nu4; float ncm1, num1, nup4;
        if (it + 1 < ITERS) {             // prefetch next row pair
            const int r  = rowBase + (it + 1) * 2 + half;
            const int ru = (r + IMG_H - 1) & (IMG_H - 1);
            nc4  = *reinterpret_cast<const float4*>(base + (size_t)r  * IMG_W + jj);
            nu4  = *reinterpret_cast<const float4*>(base + (size_t)ru * IMG_W + jj);
            ncm1 = base[(size_t)r  * IMG_W + jm1];
            num1 = base[(size_t)ru * IMG_W + jm1];
            nup4 = base[(size_t)ru * IMG_W + jp4];
        }

        int qc[5];   // qc[0]=left-of-first, qc[1..4]=the 4 pixels
        int qu[6];   // qu[0]=up-left, qu[1..4]=up row, qu[5]=up-right-of-last
        qc[0] = (int)(cm1 * 15.0f);
        qc[1] = (int)(c4.x * 15.0f); qc[2] = (int)(c4.y * 15.0f);
        qc[3] = (int)(c4.z * 15.0f); qc[4] = (int)(c4.w * 15.0f);
        qu[0] = (int)(um1 * 15.0f);
        qu[1] = (int)(u4.x * 15.0f); qu[2] = (int)(u4.y * 15.0f);
        qu[3] = (int)(u4.z * 15.0f); qu[4] = (int)(u4.w * 15.0f);
        qu[5] = (int)(up4 * 15.0f);

        // bin = q*16 + s; word = (q*8 + (s>>1))*64 + lane; field = s&1
        #pragma unroll
        for (int k = 0; k < 4; ++k) {
            const int rb = (qc[k + 1] << 9) + lane;   // q*512 + lane
            const int s0 = qc[k];       // angle   0 (left)
            const int s1 = qu[k + 2];   // angle  45 (up-right)
            const int s2 = qu[k + 1];   // angle  90 (up)
            const int s3 = qu[k];       // angle 135 (up-left)
            atomicAdd(&lh[rb + ((s0 >> 1) << 6)], 1u << ((s0 & 1) << 4));
            atomicAdd(&lh[rb + ((s1 >> 1) << 6)], 1u << ((s1 & 1) << 4));
            atomicAdd(&lh[rb + ((s2 >> 1) << 6)], 1u << ((s2 & 1) << 4));
            atomicAdd(&lh[rb + ((s3 >> 1) << 6)], 1u << ((s3 & 1) << 4));
        }

        c4 = nc4; u4 = nu4; cm1 = ncm1; um1 = num1; up4 = nup4;
    }

    __syncthreads();
    // Merge: thread t sums bin-pair p = t&127 over lane half (t>>7).
    // Rotated lane order keeps each wave's reads conflict-free.
    const int p  = tid & 127;
    const int hf = tid >> 7;
    unsigned int slo = 0, shi = 0;
    #pragma unroll
    for (int i = 0; i < 32; ++i) {
        const int l = (hf << 5) + ((p + i) & 31);
        const unsigned int w = lh[(p << 6) + l];
        slo += w & 0xffffu;
        shi += w >> 16;
    }
    __syncthreads();                 // lh reads done; reuse lh[0..255] as scratch
    if (hf) { lh[p] = slo; lh[128 + p] = shi; }
    __syncthreads();
    if (!hf) {
        const size_t ob = (size_t)(img * NSTRIPS + strip) * NBINS;
        partial[ob + 2 * p]     = slo + lh[p];
        partial[ob + 2 * p + 1] = shi + lh[128 + p];
    }
}

// ---------------------------------------------------------------------------
// Kernel 2: fused entropy + broadcast-fill. 2048 blocks = 128 images x 16.
// Each block redundantly computes its image's entropy from the 8 strip
// partials (L2-hot), then fills its 1/16 slice with nontemporal stores.
// counts.sum() == 4*H*W == 2^20 exactly.
// ---------------------------------------------------------------------------
__global__ __launch_bounds__(256) void glcm_entfill_kernel(
    const unsigned int* __restrict__ partial, float* __restrict__ out) {

    __shared__ float psum[4];
    __shared__ float ent_s;
    const int tid = threadIdx.x;
    const int bid = blockIdx.x;
    const int img = bid >> 4;
    const int sub = bid & 15;

    unsigned int c = 0;
    #pragma unroll
    for (int s = 0; s < NSTRIPS; ++s)
        c += partial[(size_t)(img * NSTRIPS + s) * NBINS + tid];

    const float p = (float)c * (1.0f / 1048576.0f);   // exact pow2 scale
    float t = p * logf(p + 1e-10f);
    #pragma unroll
    for (int off = 32; off > 0; off >>= 1) t += __shfl_down(t, off, 64);
    if ((tid & 63) == 0) psum[tid >> 6] = t;
    __syncthreads();
    if (tid == 0) ent_s = -(psum[0] + psum[1] + psum[2] + psum[3]);
    __syncthreads();

    const float e = ent_s;
    const f32x4 v = {e, e, e, e};
    f32x4* ob = reinterpret_cast<f32x4*>(out) +
                (size_t)img * (IMG_HW / 4) + (size_t)sub * (IMG_HW / 4 / FILL_PER_IMG);
    #pragma unroll
    for (int i = tid; i < IMG_HW / 4 / FILL_PER_IMG; i += 256)   // 16 stores/thread
        __builtin_nontemporal_store(v, ob + i);
}

extern "C" void kernel_launch(void* const* d_in, const int* in_sizes, int n_in,
                              void* d_out, int out_size, void* d_ws, size_t ws_size,
                              hipStream_t stream) {
    const float* x = (const float*)d_in[0];
    float* out = (float*)d_out;
    unsigned int* partial = (unsigned int*)d_ws;   // 128*8*256 u32 = 1 MB

    glcm_hist_kernel<<<N_IMG * NSTRIPS, 256, 0, stream>>>(x, partial);
    glcm_entfill_kernel<<<N_IMG * FILL_PER_IMG, 256, 0, stream>>>(partial, out);
}